// Round 1
// baseline (16.239 us; speedup 1.0000x reference)
//
#include <hip/hip_runtime.h>
#include <math.h>

#define EPS 1e-7f

// Problem constants (from the reference):
// B=64, C=18, na=3; scales: 160x160, 80x80, 40x40
// obj channel for anchor a is c = a*6 + 4
// Only boxes[63] contributes to box loss / positive cell (reference bug kept).

__device__ __forceinline__ float softplus_fast(float x) {
    // log(1+exp(x)) = max(x,0) + log(1+exp(-|x|)); |arg| of exp <= 0 -> e in (0,1]
    float e = __expf(-fabsf(x));
    return fmaxf(x, 0.0f) + __logf(1.0f + e);
}

// Sum softplus over obj channels of one scale, scaled by invN, grid-strided.
// HW4 = H*W/4 (vec4 groups per plane), NPLANES = B*na = 192.
template <int HW4>
__device__ float scale_obj_sum(const float* __restrict__ p, int tid, int nth,
                               float invN) {
    const int NV = 192 * HW4;
    float acc = 0.0f;
    for (int i = tid; i < NV; i += nth) {
        int pix4  = i % HW4;          // compile-time const -> magic mul
        int plane = i / HW4;
        int b = plane / 3;
        int a = plane - b * 3;
        const float4* src = reinterpret_cast<const float4*>(p)
                          + (size_t)(b * 18 + a * 6 + 4) * HW4 + pix4;
        float4 v = *src;
        acc += softplus_fast(v.x) + softplus_fast(v.y)
             + softplus_fast(v.z) + softplus_fast(v.w);
    }
    return acc * invN;
}

__global__ __launch_bounds__(256)
void yolo_obj_reduce(const float* __restrict__ p0,
                     const float* __restrict__ p1,
                     const float* __restrict__ p2,
                     float* __restrict__ partials) {
    const int tid = blockIdx.x * blockDim.x + threadIdx.x;
    const int nth = gridDim.x * blockDim.x;
    float acc = scale_obj_sum<6400>(p0, tid, nth, 1.0f / 4915200.0f)
              + scale_obj_sum<1600>(p1, tid, nth, 1.0f / 1228800.0f)
              + scale_obj_sum< 400>(p2, tid, nth, 1.0f /  307200.0f);
    // wave(64) shuffle reduce
    for (int off = 32; off > 0; off >>= 1) acc += __shfl_down(acc, off, 64);
    __shared__ float smem[4];
    if ((threadIdx.x & 63) == 0) smem[threadIdx.x >> 6] = acc;
    __syncthreads();
    if (threadIdx.x == 0)
        partials[blockIdx.x] = smem[0] + smem[1] + smem[2] + smem[3];
}

__global__ __launch_bounds__(256)
void yolo_finalize(const float* __restrict__ p0,
                   const float* __restrict__ p1,
                   const float* __restrict__ p2,
                   const float* __restrict__ boxes,
                   const float* __restrict__ partials,
                   float* __restrict__ out) {
    float acc = 0.0f;
    for (int i = threadIdx.x; i < 1024; i += 256) acc += partials[i];
    for (int off = 32; off > 0; off >>= 1) acc += __shfl_down(acc, off, 64);
    __shared__ float smem[4];
    if ((threadIdx.x & 63) == 0) smem[threadIdx.x >> 6] = acc;
    __syncthreads();
    if (threadIdx.x != 0) return;

    const float obj_sum = smem[0] + smem[1] + smem[2] + smem[3];

    const float anch[3][3][2] = {
        {{1.25f, 1.625f}, {2.0f, 3.75f}, {4.125f, 2.875f}},
        {{1.875f, 3.8125f}, {3.875f, 2.8125f}, {3.6875f, 7.4375f}},
        {{3.625f, 2.8125f}, {4.875f, 6.1875f}, {11.65625f, 10.1875f}},
    };
    const int   dims[3] = {160, 80, 40};
    const float invN[3] = {1.0f / 4915200.0f, 1.0f / 1228800.0f,
                           1.0f / 307200.0f};
    const float* preds[3] = {p0, p1, p2};

    // last batch element only (reference overwrites indices each iter)
    const float bx = boxes[63 * 4 + 0];
    const float by = boxes[63 * 4 + 1];
    const float bw = boxes[63 * 4 + 2];
    const float bh = boxes[63 * 4 + 3];

    float box_loss = 0.0f;
    float obj_loss = obj_sum;

    for (int s = 0; s < 3; ++s) {
        const int W = dims[s], H = dims[s];
        const float gx = bx * W, gy = by * H, gw = bw * W, gh = bh * H;
        int gi = (int)gx; gi = gi < 0 ? 0 : (gi > W - 1 ? W - 1 : gi);
        int gj = (int)gy; gj = gj < 0 ? 0 : (gj > H - 1 ? H - 1 : gj);

        int best = 0; float bestv = -1e30f;
        for (int a = 0; a < 3; ++a) {
            const float aw = anch[s][a][0], ah = anch[s][a][1];
            const float inter = fminf(gw, aw) * fminf(gh, ah);
            const float uni   = gw * gh + aw * ah - inter + EPS;
            const float v = inter / uni;
            if (v > bestv) { bestv = v; best = a; }  // first-wins tie like argmax
        }

        const float* P = preds[s];
        const size_t HW = (size_t)W * H;
        const size_t base = ((size_t)63 * 18 + (size_t)best * 6) * HW
                          + (size_t)gj * W + (size_t)gi;
        const float ps0 = P[base];
        const float ps1 = P[base + HW];
        const float ps2 = P[base + 2 * HW];
        const float ps3 = P[base + 3 * HW];
        const float ps4 = P[base + 4 * HW];

        obj_loss -= ps4 * invN[s];  // - x_pos * t / N

        // decoded prediction box (grid units)
        const float sx = 1.0f / (1.0f + expf(-ps0));
        const float sy = 1.0f / (1.0f + expf(-ps1));
        const float hw_ = expf(ps2) * anch[s][best][0] * 0.5f;
        const float hh_ = expf(ps3) * anch[s][best][1] * 0.5f;
        const float x1 = sx - hw_, y1 = sy - hh_;
        const float x2 = sx + hw_, y2 = sy + hh_;
        // target box (normalized units, as in reference)
        const float tx1 = bx - bw * 0.5f, ty1 = by - bh * 0.5f;
        const float tx2 = bx + bw * 0.5f, ty2 = by + bh * 0.5f;

        const float w1 = x2 - x1, h1 = fmaxf(y2 - y1, EPS);
        const float w2 = tx2 - tx1, h2 = fmaxf(ty2 - ty1, EPS);
        const float iw = fmaxf(fminf(x2, tx2) - fmaxf(x1, tx1), 0.0f);
        const float ih = fmaxf(fminf(y2, ty2) - fmaxf(y1, ty1), 0.0f);
        const float inter = iw * ih;
        const float uni = w1 * h1 + w2 * h2 - inter + EPS;
        const float iou = inter / uni;

        const float cw = fmaxf(x2, tx2) - fminf(x1, tx1);
        const float chh = fmaxf(y2, ty2) - fminf(y1, ty1);
        const float ddx = tx1 + tx2 - x1 - x2;
        const float ddy = ty1 + ty2 - y1 - y2;
        const float rho2 = (ddx * ddx + ddy * ddy) * 0.25f;
        const float c2 = cw * cw + chh * chh + EPS;
        const float dw = w2 - w1, dh = h2 - h1;
        const float eiou = iou - (rho2 / c2 + dw * dw / (cw * cw + EPS)
                                           + dh * dh / (chh * chh + EPS));
        box_loss += sqrtf(iou) * (1.0f - eiou);
    }

    const float total = 0.1f * box_loss + 1.0f * obj_loss;  // cls = 0
    out[0] = total;      // return value: total
    out[1] = box_loss;   // loss_items[0]
    out[2] = obj_loss;   // loss_items[1]
    out[3] = 0.0f;       // loss_items[2] (cls)
    out[4] = total;      // loss_items[3]
}

extern "C" void kernel_launch(void* const* d_in, const int* in_sizes, int n_in,
                              void* d_out, int out_size, void* d_ws,
                              size_t ws_size, hipStream_t stream) {
    const float* p0    = (const float*)d_in[0];
    const float* p1    = (const float*)d_in[1];
    const float* p2    = (const float*)d_in[2];
    const float* boxes = (const float*)d_in[3];
    // d_in[4] = labels (unused: nc==1, cls branch inactive)
    float* out      = (float*)d_out;
    float* partials = (float*)d_ws;  // 1024 floats, fully rewritten each call

    yolo_obj_reduce<<<1024, 256, 0, stream>>>(p0, p1, p2, partials);
    yolo_finalize<<<1, 256, 0, stream>>>(p0, p1, p2, boxes, partials, out);
}